// Round 10
// baseline (738.410 us; speedup 1.0000x reference)
//
#include <hip/hip_runtime.h>
#include <math.h>

// Scattering net: four-step register FFT (128 = 16 reg-DFT x 8 cross-group DFT).
// Thread (g=tid>>7, q=tid&127) owns 16 elements x[q][g+8m] of each line.
// Spectral storage permutation per axis: k = k1 + 16*k2 -> position p = 8*k1 + k2.
// psi pre-permuted into this layout (both axes) with 1/16384 folded in.
//
// Round-10 (on r9: bf16-packed LDS plane -> 66 KB, 2 blocks/CU, 87% occupancy,
// VALU-issue saturated). Pressure-neutral instruction cuts only:
//  * packbf via v_perm_b32 (__builtin_amdgcn_perm): 5 -> 3 inst per pack,
//    identical round-half-up numerics. 48 packs per fft2.
//  * k_scat_b merges the two l2 of a pair per block (7,680 blocks x 2 iffts):
//    same U for both -> U hoisted as 16 PACKED u32 regs (not 32 floats -- the
//    64-VGPR wall, r2/5/7), amortizes preamble + block-reduce + atomic.
// Tripwire: WRITE_SIZE >~1 MB on scat_b means the merge spilled -> revert.

#define SDIM 128
#define PLANE 16384
#define PITCH 129            // in storage elements
#define NT 1024
#define TWO_PI 6.28318530717958647692f

constexpr float W16R[8] = {1.f, 0.9238795325f, 0.7071067812f, 0.3826834324f,
                           0.f, -0.3826834324f, -0.7071067812f, -0.9238795325f};
constexpr float W16I[8] = {0.f, -0.3826834324f, -0.7071067812f, -0.9238795325f,
                           -1.f, -0.9238795325f, -0.7071067812f, -0.3826834324f};

// ---- packed bf16 complex <-> fp32 pair ----
// round half up on both halves, then one v_perm_b32 picks {re[31:16], im[31:16]}.
__device__ __forceinline__ unsigned packbf(float re, float im) {
  const unsigned r = __float_as_uint(re) + 0x8000u;
  const unsigned i = __float_as_uint(im) + 0x8000u;
  return __builtin_amdgcn_perm(r, i, 0x07060302u);   // D = r.b3 r.b2 i.b3 i.b2
}
__device__ __forceinline__ void unpackbf(unsigned u, float& re, float& im) {
  re = __uint_as_float(u & 0xFFFF0000u);
  im = __uint_as_float(u << 16);
}

// storage-polymorphic LDS access
__device__ __forceinline__ void stC(float2* s, int idx, float re, float im) { s[idx] = make_float2(re, im); }
__device__ __forceinline__ void ldC(const float2* s, int idx, float& re, float& im) { const float2 v = s[idx]; re = v.x; im = v.y; }
__device__ __forceinline__ void stC(unsigned* s, int idx, float re, float im) { s[idx] = packbf(re, im); }
__device__ __forceinline__ void ldC(const unsigned* s, int idx, float& re, float& im) { unpackbf(s[idx], re, im); }

// butterfly with w = W16^idx (idx compile-time constant after unroll).
template<bool INV>
__device__ __forceinline__ void bfly(float& ar, float& ai, float& br, float& bi, const int idx) {
  float tr, ti;
  if (idx == 0) {                       // w = 1
    tr = br; ti = bi;
  } else if (idx == 4) {                // w = -i (fwd) / +i (inv)
    if (INV) { tr = -bi; ti = br; } else { tr = bi; ti = -br; }
  } else {
    const float wr = W16R[idx];
    const float wi = INV ? -W16I[idx] : W16I[idx];
    tr = br * wr - bi * wi;
    ti = br * wi + bi * wr;
  }
  br = ar - tr; bi = ai - ti;
  ar = ar + tr; ai = ai + ti;
}

#define CSWAP(re, im, a, b) { float _t = re[a]; re[a]=re[b]; re[b]=_t; _t = im[a]; im[a]=im[b]; im[b]=_t; }

template<bool INV>
__device__ __forceinline__ void dft16(float* re, float* im) {
  CSWAP(re, im, 1, 8) CSWAP(re, im, 2, 4) CSWAP(re, im, 3, 12)
  CSWAP(re, im, 5, 10) CSWAP(re, im, 7, 14) CSWAP(re, im, 11, 13)
#pragma unroll
  for (int ls = 1; ls <= 4; ++ls) {
    const int len = 1 << ls, half = len >> 1, tstep = 16 >> ls;
#pragma unroll
    for (int blk = 0; blk < 16; blk += len)
#pragma unroll
      for (int j = 0; j < half; ++j)
        bfly<INV>(re[blk + j], im[blk + j], re[blk + j + half], im[blk + j + half], j * tstep);
  }
}

template<bool INV>
__device__ __forceinline__ void dft8(float* re, float* im) {
  CSWAP(re, im, 1, 4) CSWAP(re, im, 3, 6)
#pragma unroll
  for (int ls = 1; ls <= 3; ++ls) {
    const int len = 1 << ls, half = len >> 1, tstep = 8 >> ls;
#pragma unroll
    for (int blk = 0; blk < 8; blk += len)
#pragma unroll
      for (int j = 0; j < half; ++j)
        bfly<INV>(re[blk + j], im[blk + j], re[blk + j + half], im[blk + j + half], j * tstep * 2);
  }
}

// tw points at sTw + 16*g (LDS, wave-uniform -> broadcast). tw[0]=1: skip k=0.
__device__ __forceinline__ void twmul_fwd(float* R, float* I, const float2* tw) {
#pragma unroll
  for (int k = 1; k < 16; ++k) {
    const float2 w = tw[k];
    const float r = R[k] * w.x - I[k] * w.y;
    I[k] = R[k] * w.y + I[k] * w.x; R[k] = r;
  }
}
__device__ __forceinline__ void twmul_inv(float* R, float* I, const float2* tw) {
#pragma unroll
  for (int k = 1; k < 16; ++k) {
    const float2 w = tw[k];
    const float r = R[k] * w.x + I[k] * w.y;
    I[k] = I[k] * w.x - R[k] * w.y; R[k] = r;
  }
}

// Forward fft2. In: x regs, R[m] = row q element (g+8m).
// Out: col-spectral regs: R[k2] <-> plane pos (16g+k2, q), R[8+k2] <-> (16g+8+k2, q).
template<typename S>
__device__ __forceinline__ void fwd_fft2(float* R, float* I, S* sC,
                                         int g, int q, const float2* tw) {
  const int rb = q * PITCH;
  dft16<false>(R, I);
  twmul_fwd(R, I, tw);
  __syncthreads();                             // B0
#pragma unroll
  for (int k = 0; k < 16; ++k) stC(sC, rb + 8 * k + g, R[k], I[k]);
  __syncthreads();                             // B1
#pragma unroll
  for (int t = 0; t < 8; ++t) {
    ldC(sC, rb + 16 * g + t, R[t], I[t]);
    ldC(sC, rb + 16 * g + 8 + t, R[8 + t], I[8 + t]);
  }
  dft8<false>(R, I); dft8<false>(R + 8, I + 8);
#pragma unroll
  for (int k2 = 0; k2 < 8; ++k2) {             // same cells: no barrier
    stC(sC, rb + 16 * g + k2, R[k2], I[k2]);
    stC(sC, rb + 16 * g + 8 + k2, R[8 + k2], I[8 + k2]);
  }
  __syncthreads();                             // B2
#pragma unroll
  for (int m = 0; m < 16; ++m) ldC(sC, (g + 8 * m) * PITCH + q, R[m], I[m]);
  dft16<false>(R, I);
  twmul_fwd(R, I, tw);
#pragma unroll
  for (int k = 0; k < 16; ++k) stC(sC, (8 * k + g) * PITCH + q, R[k], I[k]);  // same cells
  __syncthreads();                             // B3
#pragma unroll
  for (int t = 0; t < 8; ++t) {
    ldC(sC, (16 * g + t) * PITCH + q, R[t], I[t]);
    ldC(sC, (16 * g + 8 + t) * PITCH + q, R[8 + t], I[8 + t]);
  }
  dft8<false>(R, I); dft8<false>(R + 8, I + 8);
}

// Inverse fft2 (unscaled; psi carries 1/16384). In: col-spectral regs.
// Out: x regs, R[m] = row q elem (g+8m). FIRST=true: no prior LDS consumers -> skip B0.
template<bool FIRST, typename S>
__device__ __forceinline__ void inv_fft2(float* R, float* I, S* sC,
                                         int g, int q, const float2* tw) {
  dft8<true>(R, I); dft8<true>(R + 8, I + 8);
  if constexpr (!FIRST) __syncthreads();       // B0
#pragma unroll
  for (int t = 0; t < 8; ++t) {
    stC(sC, (16 * g + t) * PITCH + q, R[t], I[t]);
    stC(sC, (16 * g + 8 + t) * PITCH + q, R[8 + t], I[8 + t]);
  }
  __syncthreads();                             // B1
#pragma unroll
  for (int k = 0; k < 16; ++k) ldC(sC, (8 * k + g) * PITCH + q, R[k], I[k]);
  twmul_inv(R, I, tw);
  dft16<true>(R, I);
#pragma unroll
  for (int m = 0; m < 16; ++m) stC(sC, (g + 8 * m) * PITCH + q, R[m], I[m]);  // same cells
  __syncthreads();                             // B2
  const int rb = q * PITCH;
#pragma unroll
  for (int k2 = 0; k2 < 8; ++k2) {
    ldC(sC, rb + 16 * g + k2, R[k2], I[k2]);
    ldC(sC, rb + 16 * g + 8 + k2, R[8 + k2], I[8 + k2]);
  }
  dft8<true>(R, I); dft8<true>(R + 8, I + 8);
#pragma unroll
  for (int t = 0; t < 8; ++t) {                // same cells: no barrier
    stC(sC, rb + 16 * g + t, R[t], I[t]);
    stC(sC, rb + 16 * g + 8 + t, R[8 + t], I[8 + t]);
  }
  __syncthreads();                             // B3
#pragma unroll
  for (int k = 0; k < 16; ++k) ldC(sC, rb + 8 * k + g, R[k], I[k]);
  twmul_inv(R, I, tw);
  dft16<true>(R, I);
}

__device__ __forceinline__ float block_reduce_sum(float v, float* red, int tid) {
#pragma unroll
  for (int o = 32; o > 0; o >>= 1) v += __shfl_down(v, o);
  __syncthreads();
  if ((tid & 63) == 0) red[tid >> 6] = v;
  __syncthreads();
  float t = 0.0f;
  if (tid == 0) {
#pragma unroll
    for (int w = 0; w < 16; ++w) t += red[w];
  }
  return t;
}

// psi in sigma x sigma spectral-position layout, 1/16384 folded in.
// Block 0 also fills the w128^{g*k} twiddle table into twg.
__global__ __launch_bounds__(256) void k_psi(const float* __restrict__ mags,
                                             const float* __restrict__ phases,
                                             float2* __restrict__ psi,
                                             float2* __restrict__ twg) {
  if (blockIdx.x == 0 && threadIdx.x < 128) {
    const int gg = threadIdx.x >> 4, k = threadIdx.x & 15;
    float sn, cs;
    __sincosf(-TWO_PI * (float)(gg * k) * (1.0f / 128.0f), &sn, &cs);
    twg[threadIdx.x] = make_float2(cs, sn);
  }
  const int gid = blockIdx.x * 256 + threadIdx.x;      // < 24*16384
  const int p = gid >> 14;
  const int pos = gid & (PLANE - 1);
  const int pr = pos >> 7, pc = pos & 127;
  const int kr = (pr >> 3) + 16 * (pr & 7);            // sigma^-1
  const int kc = (pc >> 3) + 16 * (pc & 7);
  const int src = (p << 14) + kr * SDIM + kc;
  const float m = mags[src] * (1.0f / 16384.0f);
  float sn, cs;
  __sincosf(phases[src], &sn, &cs);
  psi[gid] = make_float2(m * cs, m * sn);
}

// fp32 LDS: Xf feeds everything downstream; this kernel is ~5 us.
__global__ __launch_bounds__(NT) void k_img_fft(const float* __restrict__ img,
                                                float2* __restrict__ Xf,
                                                float* __restrict__ s0,
                                                const float2* __restrict__ twg) {
  __shared__ float2 sC[SDIM * PITCH];
  __shared__ float2 sTw[128];
  __shared__ float red[16];
  const int tid = threadIdx.x, b = blockIdx.x;
  const int g = tid >> 7, q = tid & 127;
  if (tid < 128) sTw[tid] = twg[tid];
  const float2* tw = sTw + 16 * g;
  const float* ip = img + b * PLANE;
  float sum = 0.0f;
#pragma unroll
  for (int kk = 0; kk < 16; ++kk) {
    const int e = tid + kk * NT;
    const float v = ip[e];
    sC[(e >> 7) * PITCH + (e & 127)] = make_float2(v, 0.0f);
    sum += v;
  }
  const float tot = block_reduce_sum(sum, red, tid);   // syncs publish sC & sTw
  if (tid == 0) s0[b] = tot * (1.0f / 16384.0f);
  __syncthreads();
  float R[16], I[16];
#pragma unroll
  for (int m = 0; m < 16; ++m) { R[m] = sC[q * PITCH + g + 8 * m].x; I[m] = 0.0f; }
  fwd_fft2(R, I, sC, g, q, tw);
  float2* xp = Xf + b * PLANE;
#pragma unroll
  for (int k2 = 0; k2 < 8; ++k2) {
    const int p1 = (16 * g + k2) * SDIM + q;
    const int p2 = p1 + 8 * SDIM;
    xp[p1] = make_float2(R[k2], I[k2]);
    xp[p2] = make_float2(R[8 + k2], I[8 + k2]);
  }
}

// Phase A: bid<1280: (j1=bid>>8, b=(bid&255)>>2, l1=bid&3):
//   u1=|ifft2(Xf.psi1)|, U=fft2(u1) -> Ubuf (packbf) + s1. bid>=1280: s1 j=5.
__global__ __launch_bounds__(NT) void k_scat_a(const float2* __restrict__ Xf,
                                               const float2* __restrict__ psi,
                                               float* __restrict__ s1num,
                                               unsigned* __restrict__ Ubuf,
                                               const float2* __restrict__ twg) {
  __shared__ unsigned sU[SDIM * PITCH];        // 66 KB -> 2 blocks/CU
  __shared__ float2 sTw[128];
  __shared__ float red[16];
  const int tid = threadIdx.x;
  const int g = tid >> 7, q = tid & 127;
  if (tid < 128) sTw[tid] = twg[tid];
  const float2* tw = sTw + 16 * g;
  const int bid = blockIdx.x;
  float R[16], I[16];

  if (bid < 1280) {
    const int j1 = bid >> 8;
    const int b = (bid & 255) >> 2;
    const int l1 = bid & 3;
    const float2* xp = Xf + b * PLANE;
    const float2* pp = psi + (j1 * 4 + l1) * PLANE;
#pragma unroll
    for (int k2 = 0; k2 < 8; ++k2) {
      const int p1 = (16 * g + k2) * SDIM + q;
      const int p2 = p1 + 8 * SDIM;
      const float2 x1 = xp[p1], v1 = pp[p1];
      const float2 x2 = xp[p2], v2 = pp[p2];
      R[k2] = x1.x * v1.x - x1.y * v1.y;     I[k2] = x1.x * v1.y + x1.y * v1.x;
      R[8 + k2] = x2.x * v2.x - x2.y * v2.y; I[8 + k2] = x2.x * v2.y + x2.y * v2.x;
    }
    inv_fft2<true>(R, I, sU, g, q, tw);
    float s1sum = 0.0f;
#pragma unroll
    for (int m = 0; m < 16; ++m) {
      const float a = sqrtf(R[m] * R[m] + I[m] * I[m]);
      s1sum += a; R[m] = a; I[m] = 0.0f;
    }
    fwd_fft2(R, I, sU, g, q, tw);
    unsigned* up = Ubuf + (size_t)((b * 5 + j1) * 4 + l1) * PLANE;
#pragma unroll
    for (int k2 = 0; k2 < 8; ++k2) {
      const int p1 = (16 * g + k2) * SDIM + q;
      const int p2 = p1 + 8 * SDIM;
      up[p1] = packbf(R[k2], I[k2]);
      up[p2] = packbf(R[8 + k2], I[8 + k2]);
    }
    const float tot = block_reduce_sum(s1sum, red, tid);
    if (tid == 0) atomicAdd(&s1num[b * 6 + j1], tot);
  } else {
    const int idx = bid - 1280;
    const int b = idx >> 2, l = idx & 3;
    const float2* xp = Xf + b * PLANE;
    const float2* pp = psi + (20 + l) * PLANE;
#pragma unroll
    for (int k2 = 0; k2 < 8; ++k2) {
      const int p1 = (16 * g + k2) * SDIM + q;
      const int p2 = p1 + 8 * SDIM;
      const float2 x1 = xp[p1], v1 = pp[p1];
      const float2 x2 = xp[p2], v2 = pp[p2];
      R[k2] = x1.x * v1.x - x1.y * v1.y;     I[k2] = x1.x * v1.y + x1.y * v1.x;
      R[8 + k2] = x2.x * v2.x - x2.y * v2.y; I[8 + k2] = x2.x * v2.y + x2.y * v2.x;
    }
    inv_fft2<true>(R, I, sU, g, q, tw);
    float s = 0.0f;
#pragma unroll
    for (int m = 0; m < 16; ++m) s += sqrtf(R[m] * R[m] + I[m] * I[m]);
    const float tot = block_reduce_sum(s, red, tid);
    if (tid == 0) atomicAdd(&s1num[b * 6 + 5], tot);
  }
}

// one inner ifft: U (packed regs) . psi2 -> ifft2 -> sum |.|
template<bool FIRST>
__device__ __forceinline__ float scat_b_unit(const float2* __restrict__ pp,
                                             const unsigned* Upk,
                                             unsigned* sU, int g, int q, const float2* tw) {
  float R[16], I[16];
#pragma unroll
  for (int k2 = 0; k2 < 8; ++k2) {
    const int p1 = (16 * g + k2) * SDIM + q;
    const int p2 = p1 + 8 * SDIM;
    float ur1, ui1, ur2, ui2;
    unpackbf(Upk[k2], ur1, ui1);
    unpackbf(Upk[8 + k2], ur2, ui2);
    const float2 v1 = pp[p1], v2 = pp[p2];
    R[k2] = ur1 * v1.x - ui1 * v1.y;     I[k2] = ur1 * v1.y + ui1 * v1.x;
    R[8 + k2] = ur2 * v2.x - ui2 * v2.y; I[8 + k2] = ur2 * v2.y + ui2 * v2.x;
  }
  inv_fft2<FIRST>(R, I, sU, g, q, tw);
  float s = 0.0f;
#pragma unroll
  for (int m = 0; m < 16; ++m) s += sqrtf(R[m] * R[m] + I[m] * I[m]);
  return s;
}

// Phase B: 7680 blocks; each does an l2 PAIR for one (b, l1, pair).
// idx: lp = idx&1 (l2 in {2lp, 2lp+1}); t=idx>>1: l1 = t&3; t>>=2: pair = t%15; b = t/15.
// Both l2 share U -> load once as 16 PACKED u32 regs (64-VGPR wall: never unpacked-resident).
__global__ __launch_bounds__(NT) void k_scat_b(const float2* __restrict__ psi,
                                               const unsigned* __restrict__ Ubuf,
                                               float* __restrict__ s2num,
                                               const float2* __restrict__ twg) {
  __shared__ unsigned sU[SDIM * PITCH];        // 66 KB -> 2 blocks/CU
  __shared__ float2 sTw[128];
  __shared__ float red[16];
  const int tid = threadIdx.x;
  const int g = tid >> 7, q = tid & 127;
  if (tid < 128) sTw[tid] = twg[tid];
  const float2* tw = sTw + 16 * g;
  int t = blockIdx.x;
  const int lp = t & 1; t >>= 1;
  const int l1 = t & 3; t >>= 2;
  const int pair = t % 15;
  const int b = t / 15;
  int j1 = 0, base = 0;
  if (pair >= 14)      { j1 = 4; base = 14; }
  else if (pair >= 12) { j1 = 3; base = 12; }
  else if (pair >= 9)  { j1 = 2; base = 9; }
  else if (pair >= 5)  { j1 = 1; base = 5; }
  const int j2 = j1 + 1 + (pair - base);
  const unsigned* up = Ubuf + (size_t)((b * 5 + j1) * 4 + l1) * PLANE;
  unsigned Upk[16];
#pragma unroll
  for (int k2 = 0; k2 < 8; ++k2) {
    const int p1 = (16 * g + k2) * SDIM + q;
    Upk[k2] = up[p1];
    Upk[8 + k2] = up[p1 + 8 * SDIM];
  }
  const float2* pp = psi + (j2 * 4 + 2 * lp) * PLANE;
  float vsum = scat_b_unit<true>(pp, Upk, sU, g, q, tw);
  vsum += scat_b_unit<false>(pp + PLANE, Upk, sU, g, q, tw);
  const float tot = block_reduce_sum(vsum, red, tid);
  if (tid == 0) atomicAdd(&s2num[b * 15 + pair], tot);
}

// Fallback (ws too small): monolithic, U held in regs (will spill; correctness only).
__global__ __launch_bounds__(NT) void k_scat_mono(const float2* __restrict__ Xf,
                                                  const float2* __restrict__ psi,
                                                  float* __restrict__ s1num,
                                                  float* __restrict__ s2num,
                                                  const float2* __restrict__ twg) {
  __shared__ unsigned sU[SDIM * PITCH];
  __shared__ float2 sTw[128];
  __shared__ float red[16];
  const int tid = threadIdx.x;
  const int g = tid >> 7, q = tid & 127;
  if (tid < 128) sTw[tid] = twg[tid];
  const float2* tw = sTw + 16 * g;
  const int bid = blockIdx.x;
  float R[16], I[16];
  if (bid < 1280) {
    const int j1 = bid >> 8;
    const int b = (bid & 255) >> 2;
    const int l1 = bid & 3;
    const float2* xp = Xf + b * PLANE;
    const float2* pp = psi + (j1 * 4 + l1) * PLANE;
#pragma unroll
    for (int k2 = 0; k2 < 8; ++k2) {
      const int p1 = (16 * g + k2) * SDIM + q;
      const int p2 = p1 + 8 * SDIM;
      const float2 x1 = xp[p1], v1 = pp[p1];
      const float2 x2 = xp[p2], v2 = pp[p2];
      R[k2] = x1.x * v1.x - x1.y * v1.y;     I[k2] = x1.x * v1.y + x1.y * v1.x;
      R[8 + k2] = x2.x * v2.x - x2.y * v2.y; I[8 + k2] = x2.x * v2.y + x2.y * v2.x;
    }
    inv_fft2<true>(R, I, sU, g, q, tw);
    float s1sum = 0.0f;
#pragma unroll
    for (int m = 0; m < 16; ++m) {
      const float a = sqrtf(R[m] * R[m] + I[m] * I[m]);
      s1sum += a; R[m] = a; I[m] = 0.0f;
    }
    fwd_fft2(R, I, sU, g, q, tw);
    float Ur[16], Ui[16];
#pragma unroll
    for (int k = 0; k < 16; ++k) { Ur[k] = R[k]; Ui[k] = I[k]; }
    {
      const float tot = block_reduce_sum(s1sum, red, tid);
      if (tid == 0) atomicAdd(&s1num[b * 6 + j1], tot);
    }
    const int pb = (j1 * (11 - j1)) >> 1;
    int poff = (j1 + 1) * 4 * PLANE;
#pragma unroll 1
    for (int j2 = j1 + 1; j2 <= 5; ++j2) {
      float vsum = 0.0f;
#pragma unroll 1
      for (int l2 = 0; l2 < 4; ++l2) {
#pragma unroll
        for (int k2 = 0; k2 < 8; ++k2) {
          const int p1 = (16 * g + k2) * SDIM + q;
          const int p2i = p1 + 8 * SDIM;
          const float2 v1 = psi[poff + p1], v2 = psi[poff + p2i];
          R[k2] = Ur[k2] * v1.x - Ui[k2] * v1.y;
          I[k2] = Ur[k2] * v1.y + Ui[k2] * v1.x;
          R[8 + k2] = Ur[8 + k2] * v2.x - Ui[8 + k2] * v2.y;
          I[8 + k2] = Ur[8 + k2] * v2.y + Ui[8 + k2] * v2.x;
        }
        inv_fft2<false>(R, I, sU, g, q, tw);
#pragma unroll
        for (int m = 0; m < 16; ++m) vsum += sqrtf(R[m] * R[m] + I[m] * I[m]);
        poff += PLANE;
      }
      const float tot = block_reduce_sum(vsum, red, tid);
      if (tid == 0) atomicAdd(&s2num[b * 15 + pb + (j2 - j1 - 1)], tot);
    }
  } else {
    const int idx = bid - 1280;
    const int b = idx >> 2, l = idx & 3;
    const float2* xp = Xf + b * PLANE;
    const float2* pp = psi + (20 + l) * PLANE;
#pragma unroll
    for (int k2 = 0; k2 < 8; ++k2) {
      const int p1 = (16 * g + k2) * SDIM + q;
      const int p2 = p1 + 8 * SDIM;
      const float2 x1 = xp[p1], v1 = pp[p1];
      const float2 x2 = xp[p2], v2 = pp[p2];
      R[k2] = x1.x * v1.x - x1.y * v1.y;     I[k2] = x1.x * v1.y + x1.y * v1.x;
      R[8 + k2] = x2.x * v2.x - x2.y * v2.y; I[8 + k2] = x2.x * v2.y + x2.y * v2.x;
    }
    inv_fft2<true>(R, I, sU, g, q, tw);
    float s = 0.0f;
#pragma unroll
    for (int m = 0; m < 16; ++m) s += sqrtf(R[m] * R[m] + I[m] * I[m]);
    const float tot = block_reduce_sum(s, red, tid);
    if (tid == 0) atomicAdd(&s1num[b * 6 + 5], tot);
  }
}

__global__ __launch_bounds__(64) void k_final(const float* __restrict__ s0,
                                              const float* __restrict__ s1num,
                                              const float* __restrict__ s2num,
                                              const float* __restrict__ w1,
                                              const float* __restrict__ b1,
                                              const float* __restrict__ w2,
                                              const float* __restrict__ b2,
                                              const float* __restrict__ w3,
                                              const float* __restrict__ b3,
                                              float* __restrict__ out) {
  const int b = threadIdx.x;
  if (b >= 64) return;
  float x[22];
  x[0] = s0[b];
#pragma unroll
  for (int j = 0; j < 6; ++j) x[1 + j] = s1num[b * 6 + j] * (1.0f / (4.0f * 16384.0f));
#pragma unroll
  for (int p = 0; p < 15; ++p) x[7 + p] = s2num[b * 15 + p] * (1.0f / (16.0f * 16384.0f));
  float h1[16];
#pragma unroll
  for (int o = 0; o < 16; ++o) {
    float t = b1[o];
    for (int i = 0; i < 22; ++i) t += x[i] * w1[i * 16 + o];
    h1[o] = fmaxf(t, 0.0f);
  }
  float h2[16];
#pragma unroll
  for (int o = 0; o < 16; ++o) {
    float t = b2[o];
    for (int i = 0; i < 16; ++i) t += h1[i] * w2[i * 16 + o];
    h2[o] = fmaxf(t, 0.0f);
  }
  float t = b3[0];
#pragma unroll
  for (int i = 0; i < 16; ++i) t += h2[i] * w3[i];
  out[b] = 1.0f / (1.0f + expf(-t));
}

extern "C" void kernel_launch(void* const* d_in, const int* in_sizes, int n_in,
                              void* d_out, int out_size, void* d_ws, size_t ws_size,
                              hipStream_t stream) {
  (void)in_sizes; (void)n_in; (void)out_size;
  const float* image  = (const float*)d_in[0];
  const float* mags   = (const float*)d_in[1];
  const float* phases = (const float*)d_in[2];
  const float* w1 = (const float*)d_in[3];
  const float* b1 = (const float*)d_in[4];
  const float* w2 = (const float*)d_in[5];
  const float* b2 = (const float*)d_in[6];
  const float* w3 = (const float*)d_in[7];
  const float* b3 = (const float*)d_in[8];
  float* out = (float*)d_out;

  char* ws = (char*)d_ws;
  float2* psi = (float2*)ws;                       // 3,145,728 B
  float2* Xf  = (float2*)(ws + 3145728);           // 8,388,608 B
  float*  s0  = (float*)(ws + 11534336);           // 64
  float*  s1n = s0 + 64;                           // 384
  float*  s2n = s1n + 384;                         // 960
  float2* twg = (float2*)(s2n + 960);              // 128 float2
  unsigned* Ubuf = (unsigned*)(ws + 11542528);     // 83,886,080 B
  const size_t need = 11542528ull + 83886080ull;   // ~95.4 MB

  hipMemsetAsync(s1n, 0, (384 + 960) * sizeof(float), stream);
  k_psi<<<dim3(1536), dim3(256), 0, stream>>>(mags, phases, psi, twg);
  k_img_fft<<<dim3(64), dim3(NT), 0, stream>>>(image, Xf, s0, twg);
  if (ws_size >= need) {
    k_scat_a<<<dim3(1536), dim3(NT), 0, stream>>>(Xf, psi, s1n, Ubuf, twg);
    k_scat_b<<<dim3(7680), dim3(NT), 0, stream>>>(psi, Ubuf, s2n, twg);
  } else {
    k_scat_mono<<<dim3(1536), dim3(NT), 0, stream>>>(Xf, psi, s1n, s2n, twg);
  }
  k_final<<<dim3(1), dim3(64), 0, stream>>>(s0, s1n, s2n, w1, b1, w2, b2, w3, b3, out);
}

// Round 11
// 619.204 us; speedup vs baseline: 1.1925x; 1.1925x over previous
//
#include <hip/hip_runtime.h>
#include <math.h>

// Scattering net: four-step register FFT (128 = 16 reg-DFT x 8 cross-group DFT).
// Thread (g=tid>>7, q=tid&127) owns 16 elements x[q][g+8m] of each line.
// Spectral storage permutation per axis: k = k1 + 16*k2 -> position p = 8*k1 + k2.
// psi pre-permuted into this layout (both axes) with 1/16384 folded in.
//
// Round-11: REVERT r10's l2-pair merge (holding Upk[16] across inv_fft2 raised
// VGPR 32->56, occupancy 87->45% = 1 block/CU, 495->582 us: the binding resource
// is 2-blocks/CU residency, needs VGPR <=~48). Back to r9's one-ifft-per-block
// k_scat_b (15,360 blocks, VGPR 32). KEEP the v_perm_b32 pack (same temporaries
// as the 5-op sequence -> pressure-neutral, ~2 inst saved x 48 packs per fft2).

#define SDIM 128
#define PLANE 16384
#define PITCH 129            // in storage elements
#define NT 1024
#define TWO_PI 6.28318530717958647692f

constexpr float W16R[8] = {1.f, 0.9238795325f, 0.7071067812f, 0.3826834324f,
                           0.f, -0.3826834324f, -0.7071067812f, -0.9238795325f};
constexpr float W16I[8] = {0.f, -0.3826834324f, -0.7071067812f, -0.9238795325f,
                           -1.f, -0.9238795325f, -0.7071067812f, -0.3826834324f};

// ---- packed bf16 complex <-> fp32 pair ----
// round half up on both halves, then one v_perm_b32 picks {re[31:16], im[31:16]}.
__device__ __forceinline__ unsigned packbf(float re, float im) {
  const unsigned r = __float_as_uint(re) + 0x8000u;
  const unsigned i = __float_as_uint(im) + 0x8000u;
  return __builtin_amdgcn_perm(r, i, 0x07060302u);   // D = r.b3 r.b2 i.b3 i.b2
}
__device__ __forceinline__ void unpackbf(unsigned u, float& re, float& im) {
  re = __uint_as_float(u & 0xFFFF0000u);
  im = __uint_as_float(u << 16);
}

// storage-polymorphic LDS access
__device__ __forceinline__ void stC(float2* s, int idx, float re, float im) { s[idx] = make_float2(re, im); }
__device__ __forceinline__ void ldC(const float2* s, int idx, float& re, float& im) { const float2 v = s[idx]; re = v.x; im = v.y; }
__device__ __forceinline__ void stC(unsigned* s, int idx, float re, float im) { s[idx] = packbf(re, im); }
__device__ __forceinline__ void ldC(const unsigned* s, int idx, float& re, float& im) { unpackbf(s[idx], re, im); }

// butterfly with w = W16^idx (idx compile-time constant after unroll).
template<bool INV>
__device__ __forceinline__ void bfly(float& ar, float& ai, float& br, float& bi, const int idx) {
  float tr, ti;
  if (idx == 0) {                       // w = 1
    tr = br; ti = bi;
  } else if (idx == 4) {                // w = -i (fwd) / +i (inv)
    if (INV) { tr = -bi; ti = br; } else { tr = bi; ti = -br; }
  } else {
    const float wr = W16R[idx];
    const float wi = INV ? -W16I[idx] : W16I[idx];
    tr = br * wr - bi * wi;
    ti = br * wi + bi * wr;
  }
  br = ar - tr; bi = ai - ti;
  ar = ar + tr; ai = ai + ti;
}

#define CSWAP(re, im, a, b) { float _t = re[a]; re[a]=re[b]; re[b]=_t; _t = im[a]; im[a]=im[b]; im[b]=_t; }

template<bool INV>
__device__ __forceinline__ void dft16(float* re, float* im) {
  CSWAP(re, im, 1, 8) CSWAP(re, im, 2, 4) CSWAP(re, im, 3, 12)
  CSWAP(re, im, 5, 10) CSWAP(re, im, 7, 14) CSWAP(re, im, 11, 13)
#pragma unroll
  for (int ls = 1; ls <= 4; ++ls) {
    const int len = 1 << ls, half = len >> 1, tstep = 16 >> ls;
#pragma unroll
    for (int blk = 0; blk < 16; blk += len)
#pragma unroll
      for (int j = 0; j < half; ++j)
        bfly<INV>(re[blk + j], im[blk + j], re[blk + j + half], im[blk + j + half], j * tstep);
  }
}

template<bool INV>
__device__ __forceinline__ void dft8(float* re, float* im) {
  CSWAP(re, im, 1, 4) CSWAP(re, im, 3, 6)
#pragma unroll
  for (int ls = 1; ls <= 3; ++ls) {
    const int len = 1 << ls, half = len >> 1, tstep = 8 >> ls;
#pragma unroll
    for (int blk = 0; blk < 8; blk += len)
#pragma unroll
      for (int j = 0; j < half; ++j)
        bfly<INV>(re[blk + j], im[blk + j], re[blk + j + half], im[blk + j + half], j * tstep * 2);
  }
}

// tw points at sTw + 16*g (LDS, wave-uniform -> broadcast). tw[0]=1: skip k=0.
__device__ __forceinline__ void twmul_fwd(float* R, float* I, const float2* tw) {
#pragma unroll
  for (int k = 1; k < 16; ++k) {
    const float2 w = tw[k];
    const float r = R[k] * w.x - I[k] * w.y;
    I[k] = R[k] * w.y + I[k] * w.x; R[k] = r;
  }
}
__device__ __forceinline__ void twmul_inv(float* R, float* I, const float2* tw) {
#pragma unroll
  for (int k = 1; k < 16; ++k) {
    const float2 w = tw[k];
    const float r = R[k] * w.x + I[k] * w.y;
    I[k] = I[k] * w.x - R[k] * w.y; R[k] = r;
  }
}

// Forward fft2. In: x regs, R[m] = row q element (g+8m).
// Out: col-spectral regs: R[k2] <-> plane pos (16g+k2, q), R[8+k2] <-> (16g+8+k2, q).
template<typename S>
__device__ __forceinline__ void fwd_fft2(float* R, float* I, S* sC,
                                         int g, int q, const float2* tw) {
  const int rb = q * PITCH;
  dft16<false>(R, I);
  twmul_fwd(R, I, tw);
  __syncthreads();                             // B0
#pragma unroll
  for (int k = 0; k < 16; ++k) stC(sC, rb + 8 * k + g, R[k], I[k]);
  __syncthreads();                             // B1
#pragma unroll
  for (int t = 0; t < 8; ++t) {
    ldC(sC, rb + 16 * g + t, R[t], I[t]);
    ldC(sC, rb + 16 * g + 8 + t, R[8 + t], I[8 + t]);
  }
  dft8<false>(R, I); dft8<false>(R + 8, I + 8);
#pragma unroll
  for (int k2 = 0; k2 < 8; ++k2) {             // same cells: no barrier
    stC(sC, rb + 16 * g + k2, R[k2], I[k2]);
    stC(sC, rb + 16 * g + 8 + k2, R[8 + k2], I[8 + k2]);
  }
  __syncthreads();                             // B2
#pragma unroll
  for (int m = 0; m < 16; ++m) ldC(sC, (g + 8 * m) * PITCH + q, R[m], I[m]);
  dft16<false>(R, I);
  twmul_fwd(R, I, tw);
#pragma unroll
  for (int k = 0; k < 16; ++k) stC(sC, (8 * k + g) * PITCH + q, R[k], I[k]);  // same cells
  __syncthreads();                             // B3
#pragma unroll
  for (int t = 0; t < 8; ++t) {
    ldC(sC, (16 * g + t) * PITCH + q, R[t], I[t]);
    ldC(sC, (16 * g + 8 + t) * PITCH + q, R[8 + t], I[8 + t]);
  }
  dft8<false>(R, I); dft8<false>(R + 8, I + 8);
}

// Inverse fft2 (unscaled; psi carries 1/16384). In: col-spectral regs.
// Out: x regs, R[m] = row q elem (g+8m). FIRST=true: no prior LDS consumers -> skip B0.
template<bool FIRST, typename S>
__device__ __forceinline__ void inv_fft2(float* R, float* I, S* sC,
                                         int g, int q, const float2* tw) {
  dft8<true>(R, I); dft8<true>(R + 8, I + 8);
  if constexpr (!FIRST) __syncthreads();       // B0
#pragma unroll
  for (int t = 0; t < 8; ++t) {
    stC(sC, (16 * g + t) * PITCH + q, R[t], I[t]);
    stC(sC, (16 * g + 8 + t) * PITCH + q, R[8 + t], I[8 + t]);
  }
  __syncthreads();                             // B1
#pragma unroll
  for (int k = 0; k < 16; ++k) ldC(sC, (8 * k + g) * PITCH + q, R[k], I[k]);
  twmul_inv(R, I, tw);
  dft16<true>(R, I);
#pragma unroll
  for (int m = 0; m < 16; ++m) stC(sC, (g + 8 * m) * PITCH + q, R[m], I[m]);  // same cells
  __syncthreads();                             // B2
  const int rb = q * PITCH;
#pragma unroll
  for (int k2 = 0; k2 < 8; ++k2) {
    ldC(sC, rb + 16 * g + k2, R[k2], I[k2]);
    ldC(sC, rb + 16 * g + 8 + k2, R[8 + k2], I[8 + k2]);
  }
  dft8<true>(R, I); dft8<true>(R + 8, I + 8);
#pragma unroll
  for (int t = 0; t < 8; ++t) {                // same cells: no barrier
    stC(sC, rb + 16 * g + t, R[t], I[t]);
    stC(sC, rb + 16 * g + 8 + t, R[8 + t], I[8 + t]);
  }
  __syncthreads();                             // B3
#pragma unroll
  for (int k = 0; k < 16; ++k) ldC(sC, rb + 8 * k + g, R[k], I[k]);
  twmul_inv(R, I, tw);
  dft16<true>(R, I);
}

__device__ __forceinline__ float block_reduce_sum(float v, float* red, int tid) {
#pragma unroll
  for (int o = 32; o > 0; o >>= 1) v += __shfl_down(v, o);
  __syncthreads();
  if ((tid & 63) == 0) red[tid >> 6] = v;
  __syncthreads();
  float t = 0.0f;
  if (tid == 0) {
#pragma unroll
    for (int w = 0; w < 16; ++w) t += red[w];
  }
  return t;
}

// psi in sigma x sigma spectral-position layout, 1/16384 folded in.
// Block 0 also fills the w128^{g*k} twiddle table into twg.
__global__ __launch_bounds__(256) void k_psi(const float* __restrict__ mags,
                                             const float* __restrict__ phases,
                                             float2* __restrict__ psi,
                                             float2* __restrict__ twg) {
  if (blockIdx.x == 0 && threadIdx.x < 128) {
    const int gg = threadIdx.x >> 4, k = threadIdx.x & 15;
    float sn, cs;
    __sincosf(-TWO_PI * (float)(gg * k) * (1.0f / 128.0f), &sn, &cs);
    twg[threadIdx.x] = make_float2(cs, sn);
  }
  const int gid = blockIdx.x * 256 + threadIdx.x;      // < 24*16384
  const int p = gid >> 14;
  const int pos = gid & (PLANE - 1);
  const int pr = pos >> 7, pc = pos & 127;
  const int kr = (pr >> 3) + 16 * (pr & 7);            // sigma^-1
  const int kc = (pc >> 3) + 16 * (pc & 7);
  const int src = (p << 14) + kr * SDIM + kc;
  const float m = mags[src] * (1.0f / 16384.0f);
  float sn, cs;
  __sincosf(phases[src], &sn, &cs);
  psi[gid] = make_float2(m * cs, m * sn);
}

// fp32 LDS: Xf feeds everything downstream; this kernel is ~5 us.
__global__ __launch_bounds__(NT) void k_img_fft(const float* __restrict__ img,
                                                float2* __restrict__ Xf,
                                                float* __restrict__ s0,
                                                const float2* __restrict__ twg) {
  __shared__ float2 sC[SDIM * PITCH];
  __shared__ float2 sTw[128];
  __shared__ float red[16];
  const int tid = threadIdx.x, b = blockIdx.x;
  const int g = tid >> 7, q = tid & 127;
  if (tid < 128) sTw[tid] = twg[tid];
  const float2* tw = sTw + 16 * g;
  const float* ip = img + b * PLANE;
  float sum = 0.0f;
#pragma unroll
  for (int kk = 0; kk < 16; ++kk) {
    const int e = tid + kk * NT;
    const float v = ip[e];
    sC[(e >> 7) * PITCH + (e & 127)] = make_float2(v, 0.0f);
    sum += v;
  }
  const float tot = block_reduce_sum(sum, red, tid);   // syncs publish sC & sTw
  if (tid == 0) s0[b] = tot * (1.0f / 16384.0f);
  __syncthreads();
  float R[16], I[16];
#pragma unroll
  for (int m = 0; m < 16; ++m) { R[m] = sC[q * PITCH + g + 8 * m].x; I[m] = 0.0f; }
  fwd_fft2(R, I, sC, g, q, tw);
  float2* xp = Xf + b * PLANE;
#pragma unroll
  for (int k2 = 0; k2 < 8; ++k2) {
    const int p1 = (16 * g + k2) * SDIM + q;
    const int p2 = p1 + 8 * SDIM;
    xp[p1] = make_float2(R[k2], I[k2]);
    xp[p2] = make_float2(R[8 + k2], I[8 + k2]);
  }
}

// Phase A: bid<1280: (j1=bid>>8, b=(bid&255)>>2, l1=bid&3):
//   u1=|ifft2(Xf.psi1)|, U=fft2(u1) -> Ubuf (packbf) + s1. bid>=1280: s1 j=5.
__global__ __launch_bounds__(NT) void k_scat_a(const float2* __restrict__ Xf,
                                               const float2* __restrict__ psi,
                                               float* __restrict__ s1num,
                                               unsigned* __restrict__ Ubuf,
                                               const float2* __restrict__ twg) {
  __shared__ unsigned sU[SDIM * PITCH];        // 66 KB -> 2 blocks/CU
  __shared__ float2 sTw[128];
  __shared__ float red[16];
  const int tid = threadIdx.x;
  const int g = tid >> 7, q = tid & 127;
  if (tid < 128) sTw[tid] = twg[tid];
  const float2* tw = sTw + 16 * g;
  const int bid = blockIdx.x;
  float R[16], I[16];

  if (bid < 1280) {
    const int j1 = bid >> 8;
    const int b = (bid & 255) >> 2;
    const int l1 = bid & 3;
    const float2* xp = Xf + b * PLANE;
    const float2* pp = psi + (j1 * 4 + l1) * PLANE;
#pragma unroll
    for (int k2 = 0; k2 < 8; ++k2) {
      const int p1 = (16 * g + k2) * SDIM + q;
      const int p2 = p1 + 8 * SDIM;
      const float2 x1 = xp[p1], v1 = pp[p1];
      const float2 x2 = xp[p2], v2 = pp[p2];
      R[k2] = x1.x * v1.x - x1.y * v1.y;     I[k2] = x1.x * v1.y + x1.y * v1.x;
      R[8 + k2] = x2.x * v2.x - x2.y * v2.y; I[8 + k2] = x2.x * v2.y + x2.y * v2.x;
    }
    inv_fft2<true>(R, I, sU, g, q, tw);
    float s1sum = 0.0f;
#pragma unroll
    for (int m = 0; m < 16; ++m) {
      const float a = sqrtf(R[m] * R[m] + I[m] * I[m]);
      s1sum += a; R[m] = a; I[m] = 0.0f;
    }
    fwd_fft2(R, I, sU, g, q, tw);
    unsigned* up = Ubuf + (size_t)((b * 5 + j1) * 4 + l1) * PLANE;
#pragma unroll
    for (int k2 = 0; k2 < 8; ++k2) {
      const int p1 = (16 * g + k2) * SDIM + q;
      const int p2 = p1 + 8 * SDIM;
      up[p1] = packbf(R[k2], I[k2]);
      up[p2] = packbf(R[8 + k2], I[8 + k2]);
    }
    const float tot = block_reduce_sum(s1sum, red, tid);
    if (tid == 0) atomicAdd(&s1num[b * 6 + j1], tot);
  } else {
    const int idx = bid - 1280;
    const int b = idx >> 2, l = idx & 3;
    const float2* xp = Xf + b * PLANE;
    const float2* pp = psi + (20 + l) * PLANE;
#pragma unroll
    for (int k2 = 0; k2 < 8; ++k2) {
      const int p1 = (16 * g + k2) * SDIM + q;
      const int p2 = p1 + 8 * SDIM;
      const float2 x1 = xp[p1], v1 = pp[p1];
      const float2 x2 = xp[p2], v2 = pp[p2];
      R[k2] = x1.x * v1.x - x1.y * v1.y;     I[k2] = x1.x * v1.y + x1.y * v1.x;
      R[8 + k2] = x2.x * v2.x - x2.y * v2.y; I[8 + k2] = x2.x * v2.y + x2.y * v2.x;
    }
    inv_fft2<true>(R, I, sU, g, q, tw);
    float s = 0.0f;
#pragma unroll
    for (int m = 0; m < 16; ++m) s += sqrtf(R[m] * R[m] + I[m] * I[m]);
    const float tot = block_reduce_sum(s, red, tid);
    if (tid == 0) atomicAdd(&s1num[b * 6 + 5], tot);
  }
}

// Phase B: one inner ifft per block. 15360 blocks (r9 structure: VGPR 32,
// 2 blocks/CU, 87% occupancy -- do NOT hoist U into regs, r10 regression).
// idx -> l2 = idx&3; t = idx>>2; pair = t%15; t/=15; l1 = t&3; b = t>>2.
__global__ __launch_bounds__(NT) void k_scat_b(const float2* __restrict__ psi,
                                               const unsigned* __restrict__ Ubuf,
                                               float* __restrict__ s2num,
                                               const float2* __restrict__ twg) {
  __shared__ unsigned sU[SDIM * PITCH];        // 66 KB -> 2 blocks/CU
  __shared__ float2 sTw[128];
  __shared__ float red[16];
  const int tid = threadIdx.x;
  const int g = tid >> 7, q = tid & 127;
  if (tid < 128) sTw[tid] = twg[tid];
  const float2* tw = sTw + 16 * g;
  int t = blockIdx.x;
  const int l2 = t & 3; t >>= 2;
  const int pair = t % 15; t /= 15;
  const int l1 = t & 3;
  const int b = t >> 2;
  int j1 = 0, base = 0;
  if (pair >= 14)      { j1 = 4; base = 14; }
  else if (pair >= 12) { j1 = 3; base = 12; }
  else if (pair >= 9)  { j1 = 2; base = 9; }
  else if (pair >= 5)  { j1 = 1; base = 5; }
  const int j2 = j1 + 1 + (pair - base);
  const unsigned* up = Ubuf + (size_t)((b * 5 + j1) * 4 + l1) * PLANE;
  const float2* pp = psi + (j2 * 4 + l2) * PLANE;
  float R[16], I[16];
#pragma unroll
  for (int k2 = 0; k2 < 8; ++k2) {
    const int p1 = (16 * g + k2) * SDIM + q;
    const int p2 = p1 + 8 * SDIM;
    float ur1, ui1, ur2, ui2;
    unpackbf(up[p1], ur1, ui1);
    unpackbf(up[p2], ur2, ui2);
    const float2 v1 = pp[p1], v2 = pp[p2];
    R[k2] = ur1 * v1.x - ui1 * v1.y;     I[k2] = ur1 * v1.y + ui1 * v1.x;
    R[8 + k2] = ur2 * v2.x - ui2 * v2.y; I[8 + k2] = ur2 * v2.y + ui2 * v2.x;
  }
  inv_fft2<true>(R, I, sU, g, q, tw);
  float vsum = 0.0f;
#pragma unroll
  for (int m = 0; m < 16; ++m) vsum += sqrtf(R[m] * R[m] + I[m] * I[m]);
  const float tot = block_reduce_sum(vsum, red, tid);
  if (tid == 0) atomicAdd(&s2num[b * 15 + pair], tot);
}

// Fallback (ws too small): monolithic, U held in regs (will spill; correctness only).
__global__ __launch_bounds__(NT) void k_scat_mono(const float2* __restrict__ Xf,
                                                  const float2* __restrict__ psi,
                                                  float* __restrict__ s1num,
                                                  float* __restrict__ s2num,
                                                  const float2* __restrict__ twg) {
  __shared__ unsigned sU[SDIM * PITCH];
  __shared__ float2 sTw[128];
  __shared__ float red[16];
  const int tid = threadIdx.x;
  const int g = tid >> 7, q = tid & 127;
  if (tid < 128) sTw[tid] = twg[tid];
  const float2* tw = sTw + 16 * g;
  const int bid = blockIdx.x;
  float R[16], I[16];
  if (bid < 1280) {
    const int j1 = bid >> 8;
    const int b = (bid & 255) >> 2;
    const int l1 = bid & 3;
    const float2* xp = Xf + b * PLANE;
    const float2* pp = psi + (j1 * 4 + l1) * PLANE;
#pragma unroll
    for (int k2 = 0; k2 < 8; ++k2) {
      const int p1 = (16 * g + k2) * SDIM + q;
      const int p2 = p1 + 8 * SDIM;
      const float2 x1 = xp[p1], v1 = pp[p1];
      const float2 x2 = xp[p2], v2 = pp[p2];
      R[k2] = x1.x * v1.x - x1.y * v1.y;     I[k2] = x1.x * v1.y + x1.y * v1.x;
      R[8 + k2] = x2.x * v2.x - x2.y * v2.y; I[8 + k2] = x2.x * v2.y + x2.y * v2.x;
    }
    inv_fft2<true>(R, I, sU, g, q, tw);
    float s1sum = 0.0f;
#pragma unroll
    for (int m = 0; m < 16; ++m) {
      const float a = sqrtf(R[m] * R[m] + I[m] * I[m]);
      s1sum += a; R[m] = a; I[m] = 0.0f;
    }
    fwd_fft2(R, I, sU, g, q, tw);
    float Ur[16], Ui[16];
#pragma unroll
    for (int k = 0; k < 16; ++k) { Ur[k] = R[k]; Ui[k] = I[k]; }
    {
      const float tot = block_reduce_sum(s1sum, red, tid);
      if (tid == 0) atomicAdd(&s1num[b * 6 + j1], tot);
    }
    const int pb = (j1 * (11 - j1)) >> 1;
    int poff = (j1 + 1) * 4 * PLANE;
#pragma unroll 1
    for (int j2 = j1 + 1; j2 <= 5; ++j2) {
      float vsum = 0.0f;
#pragma unroll 1
      for (int l2 = 0; l2 < 4; ++l2) {
#pragma unroll
        for (int k2 = 0; k2 < 8; ++k2) {
          const int p1 = (16 * g + k2) * SDIM + q;
          const int p2i = p1 + 8 * SDIM;
          const float2 v1 = psi[poff + p1], v2 = psi[poff + p2i];
          R[k2] = Ur[k2] * v1.x - Ui[k2] * v1.y;
          I[k2] = Ur[k2] * v1.y + Ui[k2] * v1.x;
          R[8 + k2] = Ur[8 + k2] * v2.x - Ui[8 + k2] * v2.y;
          I[8 + k2] = Ur[8 + k2] * v2.y + Ui[8 + k2] * v2.x;
        }
        inv_fft2<false>(R, I, sU, g, q, tw);
#pragma unroll
        for (int m = 0; m < 16; ++m) vsum += sqrtf(R[m] * R[m] + I[m] * I[m]);
        poff += PLANE;
      }
      const float tot = block_reduce_sum(vsum, red, tid);
      if (tid == 0) atomicAdd(&s2num[b * 15 + pb + (j2 - j1 - 1)], tot);
    }
  } else {
    const int idx = bid - 1280;
    const int b = idx >> 2, l = idx & 3;
    const float2* xp = Xf + b * PLANE;
    const float2* pp = psi + (20 + l) * PLANE;
#pragma unroll
    for (int k2 = 0; k2 < 8; ++k2) {
      const int p1 = (16 * g + k2) * SDIM + q;
      const int p2 = p1 + 8 * SDIM;
      const float2 x1 = xp[p1], v1 = pp[p1];
      const float2 x2 = xp[p2], v2 = pp[p2];
      R[k2] = x1.x * v1.x - x1.y * v1.y;     I[k2] = x1.x * v1.y + x1.y * v1.x;
      R[8 + k2] = x2.x * v2.x - x2.y * v2.y; I[8 + k2] = x2.x * v2.y + x2.y * v2.x;
    }
    inv_fft2<true>(R, I, sU, g, q, tw);
    float s = 0.0f;
#pragma unroll
    for (int m = 0; m < 16; ++m) s += sqrtf(R[m] * R[m] + I[m] * I[m]);
    const float tot = block_reduce_sum(s, red, tid);
    if (tid == 0) atomicAdd(&s1num[b * 6 + 5], tot);
  }
}

__global__ __launch_bounds__(64) void k_final(const float* __restrict__ s0,
                                              const float* __restrict__ s1num,
                                              const float* __restrict__ s2num,
                                              const float* __restrict__ w1,
                                              const float* __restrict__ b1,
                                              const float* __restrict__ w2,
                                              const float* __restrict__ b2,
                                              const float* __restrict__ w3,
                                              const float* __restrict__ b3,
                                              float* __restrict__ out) {
  const int b = threadIdx.x;
  if (b >= 64) return;
  float x[22];
  x[0] = s0[b];
#pragma unroll
  for (int j = 0; j < 6; ++j) x[1 + j] = s1num[b * 6 + j] * (1.0f / (4.0f * 16384.0f));
#pragma unroll
  for (int p = 0; p < 15; ++p) x[7 + p] = s2num[b * 15 + p] * (1.0f / (16.0f * 16384.0f));
  float h1[16];
#pragma unroll
  for (int o = 0; o < 16; ++o) {
    float t = b1[o];
    for (int i = 0; i < 22; ++i) t += x[i] * w1[i * 16 + o];
    h1[o] = fmaxf(t, 0.0f);
  }
  float h2[16];
#pragma unroll
  for (int o = 0; o < 16; ++o) {
    float t = b2[o];
    for (int i = 0; i < 16; ++i) t += h1[i] * w2[i * 16 + o];
    h2[o] = fmaxf(t, 0.0f);
  }
  float t = b3[0];
#pragma unroll
  for (int i = 0; i < 16; ++i) t += h2[i] * w3[i];
  out[b] = 1.0f / (1.0f + expf(-t));
}

extern "C" void kernel_launch(void* const* d_in, const int* in_sizes, int n_in,
                              void* d_out, int out_size, void* d_ws, size_t ws_size,
                              hipStream_t stream) {
  (void)in_sizes; (void)n_in; (void)out_size;
  const float* image  = (const float*)d_in[0];
  const float* mags   = (const float*)d_in[1];
  const float* phases = (const float*)d_in[2];
  const float* w1 = (const float*)d_in[3];
  const float* b1 = (const float*)d_in[4];
  const float* w2 = (const float*)d_in[5];
  const float* b2 = (const float*)d_in[6];
  const float* w3 = (const float*)d_in[7];
  const float* b3 = (const float*)d_in[8];
  float* out = (float*)d_out;

  char* ws = (char*)d_ws;
  float2* psi = (float2*)ws;                       // 3,145,728 B
  float2* Xf  = (float2*)(ws + 3145728);           // 8,388,608 B
  float*  s0  = (float*)(ws + 11534336);           // 64
  float*  s1n = s0 + 64;                           // 384
  float*  s2n = s1n + 384;                         // 960
  float2* twg = (float2*)(s2n + 960);              // 128 float2
  unsigned* Ubuf = (unsigned*)(ws + 11542528);     // 83,886,080 B
  const size_t need = 11542528ull + 83886080ull;   // ~95.4 MB

  hipMemsetAsync(s1n, 0, (384 + 960) * sizeof(float), stream);
  k_psi<<<dim3(1536), dim3(256), 0, stream>>>(mags, phases, psi, twg);
  k_img_fft<<<dim3(64), dim3(NT), 0, stream>>>(image, Xf, s0, twg);
  if (ws_size >= need) {
    k_scat_a<<<dim3(1536), dim3(NT), 0, stream>>>(Xf, psi, s1n, Ubuf, twg);
    k_scat_b<<<dim3(15360), dim3(NT), 0, stream>>>(psi, Ubuf, s2n, twg);
  } else {
    k_scat_mono<<<dim3(1536), dim3(NT), 0, stream>>>(Xf, psi, s1n, s2n, twg);
  }
  k_final<<<dim3(1), dim3(64), 0, stream>>>(s0, s1n, s2n, w1, b1, w2, b2, w3, b3, out);
}